// Round 5
// baseline (307.483 us; speedup 1.0000x reference)
//
#include <hip/hip_runtime.h>
#include <math.h>

// Problem: SphericalHarmonicTransform, L=8, RCUT=5, N=4194304 points.
// out[81] = sum over points of (modified) solid harmonic terms.
// R5: (a) constant-alphabet collapse: Y_m(p)=tr/(p!q!) then sum with 1/s!
//     (9 distinct consts across all triple-FMAs) and deferred h_l = x0c*inv^l;
//     VOP3 fma can't take literals, so R1-R4's 95 unique 1/(p!q!s!) constants
//     forced ~2x instruction bloat (945 vs ~500 measured busy-cycles/body).
//     (b) single dispatch: last-block finalize (counter + agent-scope atomics)
//     — R4 showed ~60us of non-main dispatch/graph overhead.
// Known-good: launch_bounds(256,2); NO prefetch (R4: +28 VGPR, 2.2MB spill, 0 gain).

#define NL 8               // L
#define NACC 45            // (l,m) pairs, m<=l, l<=8
#define NBLK 1024

__device__ __forceinline__ float waveReduce(float v) {
    v += __shfl_down(v, 32);
    v += __shfl_down(v, 16);
    v += __shfl_down(v, 8);
    v += __shfl_down(v, 4);
    v += __shfl_down(v, 2);
    v += __shfl_down(v, 1);
    return v;
}

__device__ double dfact(int nn) {
    double r = 1.0;
    for (int i = 2; i <= nn; ++i) r *= (double)i;
    return r;
}

__global__ __launch_bounds__(256, 2)
void sht_main(const float* __restrict__ pos, float* __restrict__ ws,
              unsigned* __restrict__ cnt, float* __restrict__ out, int n) {
    // Factorials (exact in fp32 up to 8!) — all indexing is compile-time after
    // unroll, so these fold to literals / hoisted registers.
    const float FACT[9] = {1.f, 1.f, 2.f, 6.f, 24.f, 120.f, 720.f, 5040.f, 40320.f};

    float accr[NACC];
    float acci[NACC];
#pragma unroll
    for (int i = 0; i < NACC; ++i) { accr[i] = 0.f; acci[i] = 0.f; }

    const int tid = blockIdx.x * blockDim.x + threadIdx.x;
    const int stride = gridDim.x * blockDim.x;

    for (int i = tid; i < n; i += stride) {
        const float x = pos[3 * i + 0];
        const float y = pos[3 * i + 1];
        const float z = pos[3 * i + 2];

        const float r2 = x * x + y * y + z * z;
        const bool valid = r2 > 0.0f;
        const float inv0 = __builtin_amdgcn_rsqf(r2);      // 1/sqrt(r2)
        const float norm = r2 * inv0;                      // sqrt(r2); r2=0 -> NaN, masked below
        // cut = 0.5*(cos(norm*pi/RCUT)+1), zeroed past RCUT and at norm==0
        float cut = 0.5f * (__cosf(norm * 0.6283185307179586f) + 1.0f);
        cut = (r2 > 25.0f) ? 0.0f : cut;
        cut = valid ? cut : 0.0f;                          // also kills NaN at r2=0
        const float inv = valid ? inv0 : 1.0f;             // 1/norm (safe)
        const float x0c = z * cut;                         // fold cutoff into x0

        const float xpr = -0.5f * x, xpi = -0.5f * y;
        const float xmr = 0.5f * x, xmi = -0.5f * y;

        // powcmplx replication:
        //  n=0 -> (1,0); n=1 -> (z); n=2 -> special (r^2-i^2, 2ri);
        //  n>=3 -> "buggy" chain: r' = ar*r - ai*im; im' = ar*im + ai*r'  (uses NEW r)
        //  (chain's own k=2 real equals the special real; its imag is the buggy one
        //   and feeds k>=3)
        float a[9], b[9], c2[9], d[9];   // a=z1r b=z1i c2=z2r d=z2i
        a[0] = 1.f; b[0] = 0.f; a[1] = xpr; b[1] = xpi;
        c2[0] = 1.f; d[0] = 0.f; c2[1] = xmr; d[1] = xmi;
        a[2] = xpr * xpr - xpi * xpi; b[2] = 2.f * xpr * xpi;
        c2[2] = xmr * xmr - xmi * xmi; d[2] = 2.f * xmr * xmi;
        {
            float br = a[2];
            float bi = xpr * xpi + xpi * br;     // buggy chain imag at k=2
#pragma unroll
            for (int k = 3; k <= NL; ++k) {
                const float nr = xpr * br - xpi * bi;
                const float ni = xpr * bi + xpi * nr;   // buggy: uses nr
                br = nr; bi = ni;
                a[k] = br; b[k] = bi;
            }
        }
        {
            float br = c2[2];
            float bi = xmr * xmi + xmi * br;     // buggy chain imag at k=2
#pragma unroll
            for (int k = 3; k <= NL; ++k) {
                const float nr = xmr * br - xmi * bi;
                const float ni = xmr * bi + xmi * nr;   // buggy: uses nr
                br = nr; bi = ni;
                c2[k] = br; d[k] = bi;
            }
        }

        float sqa[9];
#pragma unroll
        for (int p = 0; p <= NL; ++p) sqa[p] = a[p] * a[p];

        // h_l = x0c * inv^l  (x0c and 1/r^l deferred out of the triple sums)
        float h[9];
        h[0] = x0c;
#pragma unroll
        for (int l = 1; l <= NL; ++l) h[l] = h[l - 1] * inv;

        // m-outer: Y_m(p) = (a_p^2 - d_q^2, a_p d_q + b_p c_q) / (p! q!), q=p-m.
        // Then sr_raw(l,m) = sum_p Y_m(p) * (1/s!), s=l-2p+m  -> only 9 distinct
        // constants across all these fmas. acc += sr_raw * h_l.
#pragma unroll
        for (int m = 0; m <= NL; ++m) {
            float Yr[9], Yi[9];
#pragma unroll
            for (int p = 0; p <= NL; ++p) {
                if (p >= m && 2 * p - m <= NL) {
                    const int q = p - m;
                    const float cpq = 1.0f / (FACT[p] * FACT[q]);  // compile-time
                    const float tr = fmaf(-d[q], d[q], sqa[p]);
                    const float ti = fmaf(a[p], d[q], b[p] * c2[q]);
                    Yr[p] = tr * cpq;
                    Yi[p] = ti * cpq;
                }
            }
#pragma unroll
            for (int l = m; l <= NL; ++l) {
                float sr = 0.f, si = 0.f;
#pragma unroll
                for (int p = 0; p <= NL; ++p) {
                    if (p >= m && 2 * p - m <= l) {
                        const int s = l - 2 * p + m;
                        const float is = 1.0f / FACT[s];           // 9 uniques
                        sr = fmaf(Yr[p], is, sr);
                        if (m > 0) si = fmaf(Yi[p], is, si);
                    }
                }
                const int ai = l * (l + 1) / 2 + m;
                accr[ai] = fmaf(sr, h[l], accr[ai]);
                if (m > 0) acci[ai] = fmaf(si, h[l], acci[ai]);
            }
        }
    }

    // ---- reduction: wave shuffle -> LDS across 4 waves -> per-block row ----
    __shared__ float red[81][5];   // [out slot][wave], padded stride
    const int lane = threadIdx.x & 63;
    const int wave = threadIdx.x >> 6;

#pragma unroll
    for (int m = 0; m <= NL; ++m) {
#pragma unroll
        for (int l = m; l <= NL; ++l) {
            const int ai = l * (l + 1) / 2 + m;
            float vr = waveReduce(accr[ai]);
            if (lane == 0) red[l * l + l + m][wave] = vr;
            if (m > 0) {
                float vi = waveReduce(acci[ai]);
                if (lane == 0) red[l * l + l - m][wave] = vi;
            }
        }
    }
    __syncthreads();

    // transposed partials: ws[slot*NBLK + block]; agent-scope store for the
    // cross-XCD last-block read (per-XCD L2s are not coherent for plain ops)
    if ((int)threadIdx.x < 81) {
        float s = 0.f;
#pragma unroll
        for (int w = 0; w < 4; ++w) s += red[threadIdx.x][w];
        __hip_atomic_store(&ws[(size_t)threadIdx.x * NBLK + blockIdx.x], s,
                           __ATOMIC_RELAXED, __HIP_MEMORY_SCOPE_AGENT);
    }
    __threadfence();
    __syncthreads();

    // ---- last block finalizes (single-dispatch; kills inter-kernel gap) ----
    __shared__ unsigned isLast;
    if (threadIdx.x == 0) {
        unsigned old = atomicAdd(cnt, 1u);
        isLast = (old == (unsigned)(gridDim.x - 1)) ? 1u : 0u;
    }
    __syncthreads();
    if (isLast) {
        for (int j = wave; j < 81; j += 4) {
            float s = 0.f;
            for (int k = lane; k < NBLK; k += 64)
                s += __hip_atomic_load(&ws[(size_t)j * NBLK + k],
                                       __ATOMIC_RELAXED, __HIP_MEMORY_SCOPE_AGENT);
            s = waveReduce(s);
            if (lane == 0) {
                int l = 0;
                while ((l + 1) * (l + 1) <= j) ++l;
                const int M = j - l * l - l;
                const int m = (M < 0) ? -M : M;
                // f = sqrt((l+m)!(l-m)!); k_l = sqrt((2l+1)/(4*3.14159)) (ref PI)
                double sc = sqrt(dfact(l + m) * dfact(l - m)) *
                            sqrt((double)(2 * l + 1) / (4.0 * 3.14159));
                if (m > 0) sc *= sqrt(2.0) * ((m & 1) ? -1.0 : 1.0);
                out[j] = (float)((double)s * sc);
            }
        }
    }
}

extern "C" void kernel_launch(void* const* d_in, const int* in_sizes, int n_in,
                              void* d_out, int out_size, void* d_ws, size_t ws_size,
                              hipStream_t stream) {
    const float* pos = (const float*)d_in[0];
    const int npts = in_sizes[0] / 3;
    float* ws = (float*)d_ws;
    unsigned* cnt = (unsigned*)(ws + (size_t)81 * NBLK);
    float* out = (float*)d_out;

    hipMemsetAsync(cnt, 0, sizeof(unsigned), stream);
    sht_main<<<NBLK, 256, 0, stream>>>(pos, ws, cnt, out, npts);
}

// Round 6
// 153.313 us; speedup vs baseline: 2.0056x; 2.0056x over previous
//
#include <hip/hip_runtime.h>
#include <math.h>

// Problem: SphericalHarmonicTransform, L=8, RCUT=5, N=4194304 points.
// out[81] = sum over points of (modified) solid harmonic terms.
// R6: decisive register experiment. The l-outer body needs ~171 live floats
//     (45 Y pairs + 81 accumulators); at VGPR=96-124 (R1-R4) the compiler must
//     rematerialize, explaining measured 121K busy-cycles/SIMD vs ~64K static.
//     launch_bounds(256,1) frees the allocator (up to 512 VGPR). Occupancy
//     drops to 4-8 waves/CU — PROVEN irrelevant here (R1 8 waves == R3 16 waves).
// Known facts: ~60us bench-vs-kernel gap is fixed harness overhead (R5 fused
//     single-dispatch still showed it — do NOT fuse, fences cost ~150us tail).
//     Transposed-ws WRITE_SIZE bloat (2.6MB) is a line-padding artifact, ~0.4us.

#define NL 8               // L
#define NACC 45            // (l,m) pairs, m<=l, l<=8
#define NBLK 1024

__device__ __forceinline__ float waveReduce(float v) {
    v += __shfl_down(v, 32);
    v += __shfl_down(v, 16);
    v += __shfl_down(v, 8);
    v += __shfl_down(v, 4);
    v += __shfl_down(v, 2);
    v += __shfl_down(v, 1);
    return v;
}

__global__ __launch_bounds__(256, 1)   // experiment: allow up to 512 VGPR
void sht_main(const float* __restrict__ pos, float* __restrict__ ws, int n) {
    // Factorials (exact in fp32 up to 8!) — folds to literals after unroll.
    const float FACT[9] = {1.f, 1.f, 2.f, 6.f, 24.f, 120.f, 720.f, 5040.f, 40320.f};

    float accr[NACC];
    float acci[NACC];
#pragma unroll
    for (int i = 0; i < NACC; ++i) { accr[i] = 0.f; acci[i] = 0.f; }

    const int tid = blockIdx.x * blockDim.x + threadIdx.x;
    const int stride = gridDim.x * blockDim.x;

    for (int i = tid; i < n; i += stride) {
        const float x = pos[3 * i + 0];
        const float y = pos[3 * i + 1];
        const float z = pos[3 * i + 2];

        const float r2 = x * x + y * y + z * z;
        const bool valid = r2 > 0.0f;
        const float inv0 = __builtin_amdgcn_rsqf(r2);      // 1/sqrt(r2)
        const float norm = r2 * inv0;                      // sqrt(r2); NaN at 0, masked
        // cut = 0.5*(cos(norm*pi/RCUT)+1), zeroed past RCUT and at norm==0
        float cut = 0.5f * (__cosf(norm * 0.6283185307179586f) + 1.0f);
        cut = (r2 > 25.0f) ? 0.0f : cut;
        cut = valid ? cut : 0.0f;                          // kills NaN at r2=0
        const float inv = valid ? inv0 : 1.0f;             // safe 1/norm
        const float x0c = z * cut;

        const float xpr = -0.5f * x, xpi = -0.5f * y;
        const float xmr = 0.5f * x, xmi = -0.5f * y;

        // powcmplx replication:
        //  n=0 -> (1,0); n=1 -> (z); n=2 -> special (r^2-i^2, 2ri);
        //  n>=3 -> buggy chain: r' = ar*r - ai*im; im' = ar*im + ai*r'  (uses NEW r)
        //  chain's k=2 real == special real; its (buggy) imag feeds k>=3.
        float a[9], b[9], c2[9], d[9];   // a=z1r b=z1i c2=z2r d=z2i
        a[0] = 1.f; b[0] = 0.f; a[1] = xpr; b[1] = xpi;
        c2[0] = 1.f; d[0] = 0.f; c2[1] = xmr; d[1] = xmi;
        a[2] = xpr * xpr - xpi * xpi; b[2] = 2.f * xpr * xpi;
        c2[2] = xmr * xmr - xmi * xmi; d[2] = 2.f * xmr * xmi;
        {
            float br = a[2];
            float bi = xpr * xpi + xpi * br;     // buggy chain imag at k=2
#pragma unroll
            for (int k = 3; k <= NL; ++k) {
                const float nr = xpr * br - xpi * bi;
                const float ni = xpr * bi + xpi * nr;   // buggy: uses nr
                br = nr; bi = ni;
                a[k] = br; b[k] = bi;
            }
        }
        {
            float br = c2[2];
            float bi = xmr * xmi + xmi * br;     // buggy chain imag at k=2
#pragma unroll
            for (int k = 3; k <= NL; ++k) {
                const float nr = xmr * br - xmi * bi;
                const float ni = xmr * bi + xmi * nr;   // buggy: uses nr
                br = nr; bi = ni;
                c2[k] = br; d[k] = bi;
            }
        }

        float sqa[9];
#pragma unroll
        for (int p = 0; p <= NL; ++p) sqa[p] = a[p] * a[p];

        // h_l = x0c * inv^l  (x0c and 1/r^l deferred out of the triple sums)
        float h[9];
        h[0] = x0c;
#pragma unroll
        for (int l = 1; l <= NL; ++l) h[l] = h[l - 1] * inv;

        // Y(p,q) = (a_p^2 - d_q^2, a_p d_q + b_p c_q) / (p! q!)   [q<=p, p+q<=8]
        // Yi(p,p) feeds only m=0 (discarded imag) -> DCE removes it.
        float Yr[9][9], Yi[9][9];
#pragma unroll
        for (int p = 0; p <= NL; ++p) {
#pragma unroll
            for (int q = 0; q <= NL; ++q) {
                if (q <= p && p + q <= NL) {
                    const float cpq = 1.0f / (FACT[p] * FACT[q]);  // compile-time
                    Yr[p][q] = fmaf(-d[q], d[q], sqa[p]) * cpq;
                    if (q != p)   // p==q only used by m=0 real part
                        Yi[p][q] = fmaf(a[p], d[q], b[p] * c2[q]) * cpq;
                }
            }
        }

        // sr(l,m) = sum_p Y(p,p-m) * (1/s!), s=l-2p+m  -> 9 distinct constants.
        // acc(l,m) += sr * h_l.
#pragma unroll
        for (int l = 0; l <= NL; ++l) {
#pragma unroll
            for (int m = 0; m <= NL; ++m) {
                if (m <= l) {
                    float sr = 0.f, si = 0.f;
#pragma unroll
                    for (int p = 0; p <= NL; ++p) {
                        if (p >= m && 2 * p - m <= l) {
                            const int q = p - m;
                            const int s = l - 2 * p + m;
                            const float is = 1.0f / FACT[s];       // 9 uniques
                            sr = fmaf(Yr[p][q], is, sr);
                            if (m > 0) si = fmaf(Yi[p][q], is, si);
                        }
                    }
                    const int ai = l * (l + 1) / 2 + m;
                    accr[ai] = fmaf(sr, h[l], accr[ai]);
                    if (m > 0) acci[ai] = fmaf(si, h[l], acci[ai]);
                }
            }
        }
    }

    // ---- reduction: wave shuffle -> LDS across 4 waves -> per-block row ----
    __shared__ float red[81][5];   // [out slot][wave], padded stride
    const int lane = threadIdx.x & 63;
    const int wave = threadIdx.x >> 6;

#pragma unroll
    for (int m = 0; m <= NL; ++m) {
#pragma unroll
        for (int l = m; l <= NL; ++l) {
            const int ai = l * (l + 1) / 2 + m;
            float vr = waveReduce(accr[ai]);
            if (lane == 0) red[l * l + l + m][wave] = vr;
            if (m > 0) {
                float vi = waveReduce(acci[ai]);
                if (lane == 0) red[l * l + l - m][wave] = vi;
            }
        }
    }
    __syncthreads();

    // transposed partials: ws[slot*NBLK + block] -> coalesced finalize reads
    if ((int)threadIdx.x < 81) {
        float s = 0.f;
#pragma unroll
        for (int w = 0; w < 4; ++w) s += red[threadIdx.x][w];
        ws[(size_t)threadIdx.x * NBLK + blockIdx.x] = s;
    }
}

__device__ double dfact(int nn) {
    double r = 1.0;
    for (int i = 2; i <= nn; ++i) r *= (double)i;
    return r;
}

// one block per output slot; 256 threads sum 1024 coalesced partials
__global__ __launch_bounds__(256)
void sht_finalize(const float* __restrict__ ws, float* __restrict__ out) {
    const int j = blockIdx.x;       // 0..80
    const int t = threadIdx.x;
    float s = 0.f;
#pragma unroll
    for (int k = 0; k < NBLK / 256; ++k)
        s += ws[(size_t)j * NBLK + k * 256 + t];
    s = waveReduce(s);

    __shared__ float red[4];
    const int lane = t & 63, wave = t >> 6;
    if (lane == 0) red[wave] = s;
    __syncthreads();
    if (t == 0) {
        float tot = red[0] + red[1] + red[2] + red[3];
        int l = 0;
        while ((l + 1) * (l + 1) <= j) ++l;
        const int M = j - l * l - l;
        const int m = (M < 0) ? -M : M;
        // f = sqrt((l+m)!(l-m)!); k_l = sqrt((2l+1)/(4*3.14159))  (ref PI=3.14159)
        double sc = sqrt(dfact(l + m) * dfact(l - m)) *
                    sqrt((double)(2 * l + 1) / (4.0 * 3.14159));
        if (m > 0) sc *= sqrt(2.0) * ((m & 1) ? -1.0 : 1.0);
        out[j] = (float)((double)tot * sc);
    }
}

extern "C" void kernel_launch(void* const* d_in, const int* in_sizes, int n_in,
                              void* d_out, int out_size, void* d_ws, size_t ws_size,
                              hipStream_t stream) {
    const float* pos = (const float*)d_in[0];
    const int npts = in_sizes[0] / 3;
    float* ws = (float*)d_ws;
    float* out = (float*)d_out;

    sht_main<<<NBLK, 256, 0, stream>>>(pos, ws, npts);
    sht_finalize<<<81, 256, 0, stream>>>(ws, out);
}

// Round 7
// 139.939 us; speedup vs baseline: 2.1973x; 1.0956x over previous
//
#include <hip/hip_runtime.h>
#include <math.h>

// Problem: SphericalHarmonicTransform, L=8, RCUT=5, N=4194304 points.
// out[81] = sum over points of (modified) solid harmonic terms.
// R7: packed-fp32 rewrite. Measured R6: 112K busy-cyc/SIMD (~875 eff instr/pt)
//     vs ~440 static, VALUBusy pinned 52%, VGPR=108 even when 512 allowed ->
//     compiler remats to keep pressure low; fix the code shape instead:
//     (a) f32x2 / v_pk_fma_f32 everywhere a natural pair exists:
//         z1||z2 power chains, (Yr,Yi), (sr,si), (accr,acci) -> ~330 slots/pt.
//     (b) 4 points/thread/chunk via 3x float4 loads (16B-aligned, 48B/pt-group)
//         -> one latency exposure per ~7K compute cycles (kills lockstep stall).
// Known facts: ~60us bench-total vs kernel gap = fixed harness overhead (R5).
//     Do NOT use launch_bounds(256,4): clamps VGPR to 64 -> 1.1GB spill (R2).
//     Do NOT fuse finalize with fences: ~150us tail (R5).

typedef float f32x2 __attribute__((ext_vector_type(2)));

#define NL 8               // L
#define NACC 45            // (l,m) pairs, m<=l, l<=8
#define NBLK 1024
#define NTHR 256

__device__ __forceinline__ f32x2 pkfma(f32x2 a, f32x2 b, f32x2 c) {
    return __builtin_elementwise_fma(a, b, c);
}

__device__ __forceinline__ float waveReduce(float v) {
    v += __shfl_down(v, 32);
    v += __shfl_down(v, 16);
    v += __shfl_down(v, 8);
    v += __shfl_down(v, 4);
    v += __shfl_down(v, 2);
    v += __shfl_down(v, 1);
    return v;
}

// One point, fully unrolled; acc pairs = (real, imag).
__device__ __forceinline__ void point_body(float x, float y, float z,
                                           f32x2* __restrict__ accp) {
    const float FACT[9] = {1.f, 1.f, 2.f, 6.f, 24.f, 120.f, 720.f, 5040.f, 40320.f};

    const float r2 = x * x + y * y + z * z;
    const bool valid = r2 > 0.0f;
    const float inv0 = __builtin_amdgcn_rsqf(r2);      // 1/sqrt(r2)
    const float norm = r2 * inv0;                      // sqrt(r2); NaN at 0, masked
    float cut = 0.5f * (__cosf(norm * 0.6283185307179586f) + 1.0f);
    cut = (r2 > 25.0f) ? 0.0f : cut;
    cut = valid ? cut : 0.0f;                          // kills NaN at r2=0
    const float inv = valid ? inv0 : 1.0f;             // safe 1/norm
    const float x0c = z * cut;

    // packed chains: lane0 = z1 (xp), lane1 = z2 (xm)
    const f32x2 w  = { -0.5f * x,  0.5f * x };         // (xpr, xmr)
    const f32x2 wi = { -0.5f * y, -0.5f * y };         // (xpi, xmi)

    // powcmplx replication:
    //  n=0 -> (1,0); n=1 -> w; n=2 -> special (r^2-i^2, 2ri);
    //  n>=3 -> buggy chain: nr = wr*br - wi*bi; ni = wr*bi + wi*nr (uses NEW nr)
    //  chain's k=2 real == special real; its (buggy) imag feeds k>=3.
    f32x2 zr[9], zi[9];
    zr[0] = f32x2{1.f, 1.f}; zi[0] = f32x2{0.f, 0.f};
    zr[1] = w;               zi[1] = wi;
    zr[2] = w * w - wi * wi;
    zi[2] = (w + w) * wi;                              // 2*wr*wi
    {
        f32x2 cr = zr[2];
        f32x2 ci = w * wi + wi * cr;                   // buggy chain imag at k=2
#pragma unroll
        for (int k = 3; k <= NL; ++k) {
            const f32x2 nr = w * cr - wi * ci;
            const f32x2 ni = w * ci + wi * nr;         // buggy: uses nr
            cr = nr; ci = ni;
            zr[k] = nr; zi[k] = ni;
        }
    }

    // unpack views (register renames, no math)
    float aa[9], bb[9], cc[9], dd[9], sqa[9];
#pragma unroll
    for (int p = 0; p <= NL; ++p) {
        aa[p] = zr[p].x;   // z1r
        cc[p] = zr[p].y;   // z2r
        bb[p] = zi[p].x;   // z1i
        dd[p] = zi[p].y;   // z2i
        sqa[p] = aa[p] * aa[p];
    }

    // h_l = x0c * inv^l  (cutoff + 1/r^l deferred out of the sums)
    float h[9];
    h[0] = x0c;
#pragma unroll
    for (int l = 1; l <= NL; ++l) h[l] = h[l - 1] * inv;

    // m-outer: Y_m(p) = (a_p^2 - d_q^2, a_p d_q + b_p c_q)/(p! q!), q=p-m (packed);
    // sr/si(l,m) = sum_p Y_m(p) * (1/s!), s=l-2p+m (9 distinct consts);
    // accp += (sr,si) * h_l. For m=0 the .y half is dead (never read) — harmless.
#pragma unroll
    for (int m = 0; m <= NL; ++m) {
        f32x2 Y[9];
#pragma unroll
        for (int p = 0; p <= NL; ++p) {
            if (p >= m && 2 * p - m <= NL) {
                const int q = p - m;
                const float cpq = 1.0f / (FACT[p] * FACT[q]);   // compile-time
                const float bc = bb[p] * cc[q];
                const f32x2 A = { -dd[q], aa[p] };
                const f32x2 B = {  dd[q], dd[q] };
                const f32x2 C = { sqa[p], bc };
                const f32x2 Yv = pkfma(A, B, C);
                Y[p] = Yv * f32x2{cpq, cpq};
            }
        }
#pragma unroll
        for (int l = m; l <= NL; ++l) {
            f32x2 s = {0.f, 0.f};
#pragma unroll
            for (int p = 0; p <= NL; ++p) {
                if (p >= m && 2 * p - m <= l) {
                    const int sidx = l - 2 * p + m;
                    const float is = 1.0f / FACT[sidx];         // 9 uniques
                    s = pkfma(Y[p], f32x2{is, is}, s);
                }
            }
            const int ai = l * (l + 1) / 2 + m;
            accp[ai] = pkfma(s, f32x2{h[l], h[l]}, accp[ai]);
        }
    }
}

__global__ __launch_bounds__(256, 2)
void sht_main(const float* __restrict__ pos, float* __restrict__ ws, int n) {
    f32x2 accp[NACC];
#pragma unroll
    for (int i = 0; i < NACC; ++i) accp[i] = f32x2{0.f, 0.f};

    const int t = blockIdx.x * NTHR + threadIdx.x;
    const int nthreads = NBLK * NTHR;                   // 262144
    const int nchunks = (n / 4 + nthreads - 1) / nthreads;  // 4 for N=2^22

    for (int c = 0; c < nchunks; ++c) {
        const int idx = (c * nthreads + t) * 4;         // 4 contiguous points
        float xs[4], ys[4], zs[4];
        if (idx + 4 <= n) {
            // 3x float4 = 48B, 16B-aligned (idx%4==0 -> 48B offset multiple)
            const float4* p4 = reinterpret_cast<const float4*>(pos + (size_t)3 * idx);
            const float4 q0 = p4[0];    // x0 y0 z0 x1
            const float4 q1 = p4[1];    // y1 z1 x2 y2
            const float4 q2 = p4[2];    // z2 x3 y3 z3
            xs[0] = q0.x; ys[0] = q0.y; zs[0] = q0.z;
            xs[1] = q0.w; ys[1] = q1.x; zs[1] = q1.y;
            xs[2] = q1.z; ys[2] = q1.w; zs[2] = q2.x;
            xs[3] = q2.y; ys[3] = q2.z; zs[3] = q2.w;
        } else {
#pragma unroll
            for (int k = 0; k < 4; ++k) {
                const int i = idx + k;
                const bool ok = i < n;
                xs[k] = ok ? pos[3 * i + 0] : 0.f;      // zero-pad: contributes 0
                ys[k] = ok ? pos[3 * i + 1] : 0.f;
                zs[k] = ok ? pos[3 * i + 2] : 0.f;
            }
        }
#pragma unroll
        for (int k = 0; k < 4; ++k)
            point_body(xs[k], ys[k], zs[k], accp);
    }

    // ---- reduction: wave shuffle -> LDS across 4 waves -> per-block row ----
    __shared__ float red[81][5];   // [out slot][wave], padded stride
    const int lane = threadIdx.x & 63;
    const int wave = threadIdx.x >> 6;

#pragma unroll
    for (int m = 0; m <= NL; ++m) {
#pragma unroll
        for (int l = m; l <= NL; ++l) {
            const int ai = l * (l + 1) / 2 + m;
            float vr = waveReduce(accp[ai].x);
            if (lane == 0) red[l * l + l + m][wave] = vr;
            if (m > 0) {
                float vi = waveReduce(accp[ai].y);
                if (lane == 0) red[l * l + l - m][wave] = vi;
            }
        }
    }
    __syncthreads();

    // transposed partials: ws[slot*NBLK + block] -> coalesced finalize reads
    if ((int)threadIdx.x < 81) {
        float s = 0.f;
#pragma unroll
        for (int w = 0; w < 4; ++w) s += red[threadIdx.x][w];
        ws[(size_t)threadIdx.x * NBLK + blockIdx.x] = s;
    }
}

__device__ double dfact(int nn) {
    double r = 1.0;
    for (int i = 2; i <= nn; ++i) r *= (double)i;
    return r;
}

// one block per output slot; 256 threads sum 1024 coalesced partials
__global__ __launch_bounds__(256)
void sht_finalize(const float* __restrict__ ws, float* __restrict__ out) {
    const int j = blockIdx.x;       // 0..80
    const int t = threadIdx.x;
    float s = 0.f;
#pragma unroll
    for (int k = 0; k < NBLK / 256; ++k)
        s += ws[(size_t)j * NBLK + k * 256 + t];
    s = waveReduce(s);

    __shared__ float red[4];
    const int lane = t & 63, wave = t >> 6;
    if (lane == 0) red[wave] = s;
    __syncthreads();
    if (t == 0) {
        float tot = red[0] + red[1] + red[2] + red[3];
        int l = 0;
        while ((l + 1) * (l + 1) <= j) ++l;
        const int M = j - l * l - l;
        const int m = (M < 0) ? -M : M;
        // f = sqrt((l+m)!(l-m)!); k_l = sqrt((2l+1)/(4*3.14159))  (ref PI=3.14159)
        double sc = sqrt(dfact(l + m) * dfact(l - m)) *
                    sqrt((double)(2 * l + 1) / (4.0 * 3.14159));
        if (m > 0) sc *= sqrt(2.0) * ((m & 1) ? -1.0 : 1.0);
        out[j] = (float)((double)tot * sc);
    }
}

extern "C" void kernel_launch(void* const* d_in, const int* in_sizes, int n_in,
                              void* d_out, int out_size, void* d_ws, size_t ws_size,
                              hipStream_t stream) {
    const float* pos = (const float*)d_in[0];
    const int npts = in_sizes[0] / 3;
    float* ws = (float*)d_ws;
    float* out = (float*)d_out;

    sht_main<<<NBLK, NTHR, 0, stream>>>(pos, ws, npts);
    sht_finalize<<<81, 256, 0, stream>>>(ws, out);
}